// Round 3
// baseline (1851.431 us; speedup 1.0000x reference)
//
#include <hip/hip_runtime.h>

typedef __attribute__((ext_vector_type(8))) _Float16 f16x8;
typedef __attribute__((ext_vector_type(4))) float f32x4;

namespace {

constexpr int H_ = 64;
constexpr int R_ = 32;
constexpr int B_ = 64;
constexpr int C_ = 256;
constexpr int T_ = 512;
constexpr int N_ = B_ * C_;   // 16384 sequences

#define MFMA16(a, b, c) __builtin_amdgcn_mfma_f32_16x16x32_f16((a), (b), (c), 0, 0, 0)

__device__ __forceinline__ float sigf(float v) {
    return 1.0f / (1.0f + __expf(-v));
}
// tanh(a) = 2*sigmoid(2a) - 1  (graceful at +/-inf)
__device__ __forceinline__ float tanhf_(float a) {
    return __fmaf_rn(2.0f, sigf(2.0f * a), -1.0f);
}

// ---------------------------------------------------------------------------
// Pack GRU weights into B-fragment-linear fp16 (same as round 2).
//  f0-1 : Whh0 r     f2-3 : Whh0 z     f4-5 : Whh0 n
//  f6-7 : Wih1 r     f8-9 : Whh1 r
//  f10-11: Wih1 z    f12-13: Whh1 z
//  f14-15: Wih1 n    f16-17: Whh1 n
// packed[((w*18 + f)*512) + lane*8 + j], k = (f&1)*32 + (lane>>4)*8 + j,
// out-row = hb + (lane&15) (+gate offset).
// ---------------------------------------------------------------------------
__global__ void pack_weights_kernel(const float* __restrict__ Whh0,
                                    const float* __restrict__ Wih1,
                                    const float* __restrict__ Whh1,
                                    _Float16* __restrict__ packed)
{
    const int b = blockIdx.x;          // 0..71
    const int w = b / 18, f = b % 18;
    const int l = threadIdx.x;         // 0..63
    const int c = l & 15, g = l >> 4;
    const int hb = w * 16;
    const int kk = f & 1;
    const float* src = Whh0;
    int row = 0;
    switch (f >> 1) {
        case 0: src = Whh0; row = hb + c;        break;
        case 1: src = Whh0; row = 64 + hb + c;   break;
        case 2: src = Whh0; row = 128 + hb + c;  break;
        case 3: src = Wih1; row = hb + c;        break;
        case 4: src = Whh1; row = hb + c;        break;
        case 5: src = Wih1; row = 64 + hb + c;   break;
        case 6: src = Whh1; row = 64 + hb + c;   break;
        case 7: src = Wih1; row = 128 + hb + c;  break;
        case 8: src = Whh1; row = 128 + hb + c;  break;
    }
    _Float16* dst = packed + ((size_t)(w * 18 + f) * 512) + (size_t)l * 8;
    #pragma unroll
    for (int j = 0; j < 8; ++j) {
        int k = kk * 32 + g * 8 + j;
        dst[j] = (_Float16)src[row * 64 + k];
    }
}

// ---------------------------------------------------------------------------
// Layer-pipelined MFMA GRU scan. Block = 16 sequences, 4 waves; wave w owns
// hid-slice w*16..+15. Phase p computes L0(p) AND L1(p-1) concurrently:
//   L0(p):   gates from h0(p-1)            -> h0(p)
//   L1(p-1): gates from h0(p-1), h1(p-2)   -> h1(p-1)
// One barrier per phase; shared A-fragments (L0 h-input == L1 x-input).
// Buffers by parity: phase p reads slot (p+1)&1, writes slot p&1.
// ---------------------------------------------------------------------------
__global__ __launch_bounds__(256)
void gru_mfma_kernel(const float* __restrict__ x,
                     const _Float16* __restrict__ packedW,
                     const float* __restrict__ Wih0,
                     const float* __restrict__ bih0,
                     const float* __restrict__ bhh0,
                     const float* __restrict__ bih1,
                     const float* __restrict__ bhh1,
                     float* __restrict__ hT_out)
{
    __shared__ __align__(16) _Float16 h0s[2][16][72];   // row stride 144 B
    __shared__ __align__(16) _Float16 h1s[2][16][72];
    __shared__ float xs_[32][17];

    const int tid = threadIdx.x;
    const int l = tid & 63;
    const int w = tid >> 6;
    const int c = l & 15, g = l >> 4;
    const int hb = w * 16;
    const int hid = hb + c;
    const int n0 = blockIdx.x * 16;

    // resident B fragments
    f16x8 B[18];
    {
        const f16x8* bp = (const f16x8*)(packedW + (size_t)w * 18 * 512);
        #pragma unroll
        for (int f = 0; f < 18; ++f) B[f] = bp[f * 64 + l];
    }

    // per-lane constants
    const float wr0 = Wih0[hid], wz0 = Wih0[64 + hid], wn0 = Wih0[128 + hid];
    const float b0r  = bhh0[hid] + bih0[hid];
    const float b0z  = bhh0[64 + hid] + bih0[64 + hid];
    const float b0nh = bhh0[128 + hid];
    const float b0nx = bih0[128 + hid];
    const float b1r  = bih1[hid] + bhh1[hid];
    const float b1z  = bih1[64 + hid] + bhh1[64 + hid];
    const float b1nx = bih1[128 + hid];
    const float b1nh = bhh1[128 + hid];

    for (int p = tid; p < 2 * 16 * 72; p += 256) {
        (&h0s[0][0][0])[p] = (_Float16)0.0f;
        (&h1s[0][0][0])[p] = (_Float16)0.0f;
    }
    float h0st[4] = {0.f, 0.f, 0.f, 0.f};
    float h1st[4] = {0.f, 0.f, 0.f, 0.f};

    auto stage_x = [&](int t0) {
        int ss = tid >> 4;
        int tb = tid & 15;
        xs_[tb][ss]      = x[(size_t)(n0 + ss) * T_ + t0 + tb];
        xs_[tb + 16][ss] = x[(size_t)(n0 + ss) * T_ + t0 + tb + 16];
    };

    auto phase = [&](int p, bool doL0, bool doL1) {
        const int pp = p & 1;
        const _Float16* h0rd = &h0s[pp ^ 1][0][0];
        // shared A-fragments: h0(p-1) feeds L0 (h-input) and L1 (x-input)
        f16x8 a00 = *(const f16x8*)(h0rd + c * 72 + g * 8);
        f16x8 a01 = *(const f16x8*)(h0rd + c * 72 + 32 + g * 8);

        if (doL0) {
            f32x4 accr = {b0r, b0r, b0r, b0r};
            f32x4 accz = {b0z, b0z, b0z, b0z};
            f32x4 accn = {b0nh, b0nh, b0nh, b0nh};
            accr = MFMA16(a00, B[0], accr);
            accz = MFMA16(a00, B[2], accz);
            accn = MFMA16(a00, B[4], accn);
            accr = MFMA16(a01, B[1], accr);
            accz = MFMA16(a01, B[3], accz);
            accn = MFMA16(a01, B[5], accn);

            if (doL1) {
                const _Float16* h1rd = &h1s[pp ^ 1][0][0];
                f16x8 ah0 = *(const f16x8*)(h1rd + c * 72 + g * 8);
                f16x8 ah1 = *(const f16x8*)(h1rd + c * 72 + 32 + g * 8);
                f32x4 r1  = {b1r, b1r, b1r, b1r};
                f32x4 z1  = {b1z, b1z, b1z, b1z};
                f32x4 xn1 = {b1nx, b1nx, b1nx, b1nx};
                f32x4 hn1 = {b1nh, b1nh, b1nh, b1nh};
                r1  = MFMA16(a00, B[6],  r1);
                z1  = MFMA16(a00, B[10], z1);
                xn1 = MFMA16(a00, B[14], xn1);
                r1  = MFMA16(a01, B[7],  r1);
                z1  = MFMA16(a01, B[11], z1);
                xn1 = MFMA16(a01, B[15], xn1);
                r1  = MFMA16(ah0, B[8],  r1);
                z1  = MFMA16(ah0, B[12], z1);
                hn1 = MFMA16(ah0, B[16], hn1);
                r1  = MFMA16(ah1, B[9],  r1);
                z1  = MFMA16(ah1, B[13], z1);
                hn1 = MFMA16(ah1, B[17], hn1);

                // L0 elementwise -> h0(p)
                #pragma unroll
                for (int q = 0; q < 4; ++q) {
                    int seq = g * 4 + q;
                    float xv = xs_[p & 31][seq];
                    float r = sigf(__fmaf_rn(xv, wr0, accr[q]));
                    float z = sigf(__fmaf_rn(xv, wz0, accz[q]));
                    float nn = tanhf_(__fmaf_rn(xv, wn0, b0nx) + r * accn[q]);
                    float hn = nn + z * (h0st[q] - nn);
                    h0st[q] = hn;
                    h0s[pp][seq][hid] = (_Float16)hn;
                }
                // L1 elementwise -> h1(p-1)
                #pragma unroll
                for (int q = 0; q < 4; ++q) {
                    int seq = g * 4 + q;
                    float r = sigf(r1[q]);
                    float z = sigf(z1[q]);
                    float nn = tanhf_(xn1[q] + r * hn1[q]);
                    float hn = nn + z * (h1st[q] - nn);
                    h1st[q] = hn;
                    h1s[pp][seq][hid] = (_Float16)hn;
                }
            } else {
                // L0 only (phase 0)
                #pragma unroll
                for (int q = 0; q < 4; ++q) {
                    int seq = g * 4 + q;
                    float xv = xs_[p & 31][seq];
                    float r = sigf(__fmaf_rn(xv, wr0, accr[q]));
                    float z = sigf(__fmaf_rn(xv, wz0, accz[q]));
                    float nn = tanhf_(__fmaf_rn(xv, wn0, b0nx) + r * accn[q]);
                    float hn = nn + z * (h0st[q] - nn);
                    h0st[q] = hn;
                    h0s[pp][seq][hid] = (_Float16)hn;
                }
            }
        } else {
            // L1 only (final phase p == T_)
            const _Float16* h1rd = &h1s[pp ^ 1][0][0];
            f16x8 ah0 = *(const f16x8*)(h1rd + c * 72 + g * 8);
            f16x8 ah1 = *(const f16x8*)(h1rd + c * 72 + 32 + g * 8);
            f32x4 r1  = {b1r, b1r, b1r, b1r};
            f32x4 z1  = {b1z, b1z, b1z, b1z};
            f32x4 xn1 = {b1nx, b1nx, b1nx, b1nx};
            f32x4 hn1 = {b1nh, b1nh, b1nh, b1nh};
            r1  = MFMA16(a00, B[6],  r1);
            z1  = MFMA16(a00, B[10], z1);
            xn1 = MFMA16(a00, B[14], xn1);
            r1  = MFMA16(a01, B[7],  r1);
            z1  = MFMA16(a01, B[11], z1);
            xn1 = MFMA16(a01, B[15], xn1);
            r1  = MFMA16(ah0, B[8],  r1);
            z1  = MFMA16(ah0, B[12], z1);
            hn1 = MFMA16(ah0, B[16], hn1);
            r1  = MFMA16(ah1, B[9],  r1);
            z1  = MFMA16(ah1, B[13], z1);
            hn1 = MFMA16(ah1, B[17], hn1);
            #pragma unroll
            for (int q = 0; q < 4; ++q) {
                float r = sigf(r1[q]);
                float z = sigf(z1[q]);
                float nn = tanhf_(xn1[q] + r * hn1[q]);
                float hn = nn + z * (h1st[q] - nn);
                h1st[q] = hn;
            }
        }
    };

    // prologue: phase 0 (L0 only)
    stage_x(0);
    __syncthreads();
    phase(0, true, false);

    // main loop: phases 1..T-1, one barrier each (+1 extra on x-stage phases)
    for (int p = 1; p < T_; ++p) {
        if ((p & 31) == 0) {
            __syncthreads();        // old xs tile fully consumed
            stage_x(p);
        }
        __syncthreads();
        phase(p, true, true);
    }

    // epilogue: phase T (L1 only)
    __syncthreads();
    phase(T_, false, true);

    #pragma unroll
    for (int q = 0; q < 4; ++q) {
        int seq = g * 4 + q;
        hT_out[(size_t)(n0 + seq) * H_ + hid] = h1st[q];
    }
}

// ---------------------------------------------------------------------------
// Heads: mu, softplus(d), v (R=32), resid = y - mu. One thread per sequence.
// ---------------------------------------------------------------------------
__global__ __launch_bounds__(256)
void heads_kernel(const float* __restrict__ hT,
                  const float* __restrict__ y,
                  const float* __restrict__ Wm, const float* __restrict__ bm,
                  const float* __restrict__ Wd, const float* __restrict__ bd,
                  const float* __restrict__ Wv, const float* __restrict__ bv,
                  float* __restrict__ v_out,
                  float* __restrict__ dd_out,
                  float* __restrict__ r_out)
{
    const int n = blockIdx.x * 256 + threadIdx.x;
    const float* h = hT + (size_t)n * H_;

    float hreg[H_];
    #pragma unroll
    for (int j = 0; j < H_; j += 4) {
        float4 q = *(const float4*)(h + j);
        hreg[j] = q.x; hreg[j + 1] = q.y; hreg[j + 2] = q.z; hreg[j + 3] = q.w;
    }
    float mu = bm[0], dv = bd[0];
    #pragma unroll
    for (int j = 0; j < H_; ++j) {
        mu = __fmaf_rn(Wm[j], hreg[j], mu);
        dv = __fmaf_rn(Wd[j], hreg[j], dv);
    }
    r_out[n]  = y[n] - mu;
    dd_out[n] = log1pf(__expf(dv));   // softplus

    for (int k = 0; k < R_; ++k) {
        float acc = bv[k];
        #pragma unroll
        for (int j = 0; j < H_; ++j)
            acc = __fmaf_rn(Wv[k * H_ + j], hreg[j], acc);
        v_out[(size_t)n * R_ + k] = acc;
    }
}

__device__ __forceinline__ float block_reduce_sum256(float* red, int tid, float val)
{
    red[tid] = val;
    __syncthreads();
    for (int off = 128; off > 0; off >>= 1) {
        if (tid < off) red[tid] += red[tid + off];
        __syncthreads();
    }
    float r = red[0];
    __syncthreads();
    return r;
}

// ---------------------------------------------------------------------------
// Per-batch Woodbury: sigma = V V^T + D.
// quad  = r^T D^-1 r - u^T M^-1 u,  u = V^T D^-1 r,  M = I + V^T D^-1 V
// logdet= sum log d + logdet M  (32x32 Cholesky)
// ---------------------------------------------------------------------------
__global__ __launch_bounds__(256)
void woodbury_kernel(const float* __restrict__ v_in,
                     const float* __restrict__ dd_in,
                     const float* __restrict__ r_in,
                     float* __restrict__ batch_out)
{
    __shared__ float Vl[C_][R_ + 1];
    __shared__ float Vw[C_][R_ + 1];
    __shared__ float wi[C_];
    __shared__ float rl[C_];
    __shared__ float red[256];
    __shared__ float MA[R_][R_ + 1];
    __shared__ float uA[R_], yA[R_], wA[R_];

    const int tid = threadIdx.x;
    const int nb  = blockIdx.x * C_;

    for (int p = tid; p < C_ * R_; p += 256) {
        int cc = p >> 5, k = p & 31;
        Vl[cc][k] = v_in[(size_t)(nb + cc) * R_ + k];
    }
    float dval = dd_in[nb + tid];
    float winv = 1.0f / dval;
    float rv   = r_in[nb + tid];
    wi[tid] = winv;
    rl[tid] = rv;
    __syncthreads();

    for (int p = tid; p < C_ * R_; p += 256) {
        int cc = p >> 5, k = p & 31;
        Vw[cc][k] = Vl[cc][k] * wi[cc];
    }
    __syncthreads();

    float slogd = block_reduce_sum256(red, tid, __logf(dval));
    float rDr   = block_reduce_sum256(red, tid, rv * rv * winv);

    #pragma unroll
    for (int e = 0; e < 4; ++e) {
        int p = tid + e * 256;
        int i = p >> 5, j = p & 31;
        float acc = (i == j) ? 1.0f : 0.0f;
        for (int cc = 0; cc < C_; ++cc)
            acc = __fmaf_rn(Vw[cc][i], Vl[cc][j], acc);
        MA[i][j] = acc;
    }
    if (tid < R_) {
        float acc = 0.0f;
        for (int cc = 0; cc < C_; ++cc)
            acc = __fmaf_rn(Vw[cc][tid], rl[cc], acc);
        uA[tid] = acc;
    }
    __syncthreads();

    for (int k = 0; k < R_; ++k) {
        if (tid == 0) MA[k][k] = sqrtf(MA[k][k]);
        __syncthreads();
        if (tid > k && tid < R_) MA[tid][k] /= MA[k][k];
        __syncthreads();
        if (tid > k && tid < R_) {
            float ljk = MA[tid][k];
            for (int i2 = k + 1; i2 <= tid; ++i2)
                MA[tid][i2] -= ljk * MA[i2][k];
        }
        __syncthreads();
    }
    float ldm = block_reduce_sum256(red, tid,
                    (tid < R_) ? 2.0f * __logf(MA[tid][tid]) : 0.0f);

    if (tid == 0) {
        for (int k = 0; k < R_; ++k) {
            float sv = uA[k];
            for (int i2 = 0; i2 < k; ++i2) sv -= MA[k][i2] * yA[i2];
            yA[k] = sv / MA[k][k];
        }
        for (int k = R_ - 1; k >= 0; --k) {
            float sv = yA[k];
            for (int i2 = k + 1; i2 < R_; ++i2) sv -= MA[i2][k] * wA[i2];
            wA[k] = sv / MA[k][k];
        }
        float uw = 0.0f;
        for (int k = 0; k < R_; ++k) uw += wA[k] * uA[k];
        batch_out[blockIdx.x] = (rDr - uw) + slogd + ldm;
    }
}

__global__ void finalize_kernel(const float* __restrict__ bws, float* __restrict__ out)
{
    float v = bws[threadIdx.x];
    #pragma unroll
    for (int off = 32; off > 0; off >>= 1)
        v += __shfl_down(v, off, 64);
    if (threadIdx.x == 0) out[0] = v * (1.0f / 64.0f);
}

} // anonymous namespace

extern "C" void kernel_launch(void* const* d_in, const int* in_sizes, int n_in,
                              void* d_out, int out_size, void* d_ws, size_t ws_size,
                              hipStream_t stream)
{
    const float* x    = (const float*)d_in[0];
    const float* y    = (const float*)d_in[1];
    const float* Wih0 = (const float*)d_in[2];
    const float* Whh0 = (const float*)d_in[3];
    const float* bih0 = (const float*)d_in[4];
    const float* bhh0 = (const float*)d_in[5];
    const float* Wih1 = (const float*)d_in[6];
    const float* Whh1 = (const float*)d_in[7];
    const float* bih1 = (const float*)d_in[8];
    const float* bhh1 = (const float*)d_in[9];
    const float* Wm   = (const float*)d_in[10];
    const float* bm   = (const float*)d_in[11];
    const float* Wd   = (const float*)d_in[12];
    const float* bd   = (const float*)d_in[13];
    const float* Wv   = (const float*)d_in[14];
    const float* bv   = (const float*)d_in[15];

    char* ws = (char*)d_ws;
    float*    hT     = (float*)(ws + 0);                 // N*64 f32   (4 MB)
    float*    v_ws   = (float*)(ws + 4194304);           // N*32 f32   (2 MB)
    float*    dd_ws  = (float*)(ws + 6291456);           // N f32
    float*    r_ws   = (float*)(ws + 6356992);           // N f32
    float*    b_ws   = (float*)(ws + 6422528);           // B f32
    _Float16* packed = (_Float16*)(ws + 6423552);        // 4*18*512 fp16 (73728 B)

    pack_weights_kernel<<<72, 64, 0, stream>>>(Whh0, Wih1, Whh1, packed);
    gru_mfma_kernel<<<N_ / 16, 256, 0, stream>>>(
        x, packed, Wih0, bih0, bhh0, bih1, bhh1, hT);
    heads_kernel<<<N_ / 256, 256, 0, stream>>>(
        hT, y, Wm, bm, Wd, bd, Wv, bv, v_ws, dd_ws, r_ws);
    woodbury_kernel<<<B_, 256, 0, stream>>>(v_ws, dd_ws, r_ws, b_ws);
    finalize_kernel<<<1, 64, 0, stream>>>(b_ws, (float*)d_out);
}

// Round 4
// 1111.439 us; speedup vs baseline: 1.6658x; 1.6658x over previous
//
#include <hip/hip_runtime.h>

typedef __attribute__((ext_vector_type(8))) _Float16 f16x8;
typedef __attribute__((ext_vector_type(4))) float f32x4;

namespace {

constexpr int H_ = 64;
constexpr int R_ = 32;
constexpr int B_ = 64;
constexpr int C_ = 256;
constexpr int T_ = 512;
constexpr int N_ = B_ * C_;   // 16384 sequences

constexpr float LOG2E  = 1.44269504088896f;
constexpr float NLOG2E = -1.44269504088896f;
constexpr float N2LOG2E = -2.88539008177793f;

#define MFMA16(a, b, c) __builtin_amdgcn_mfma_f32_16x16x32_f16((a), (b), (c), 0, 0, 0)

// sigmoid(pre + bias) with bias pre-folded: cb = -log2e * bias
__device__ __forceinline__ float sig_fold(float pre, float cb) {
    float t = __builtin_amdgcn_exp2f(__fmaf_rn(pre, NLOG2E, cb));
    return __builtin_amdgcn_rcpf(1.0f + t);
}
// tanh(a) = 2*sigmoid(2a) - 1
__device__ __forceinline__ float tanh_fast(float a) {
    float t = __builtin_amdgcn_exp2f(a * N2LOG2E);
    return __fmaf_rn(2.0f, __builtin_amdgcn_rcpf(1.0f + t), -1.0f);
}

// ---------------------------------------------------------------------------
// Pack GRU weights into B-fragment-linear fp16.
//  f0-1 : Whh0 r     f2-3 : Whh0 z     f4-5 : Whh0 n
//  f6-7 : Wih1 r     f8-9 : Whh1 r
//  f10-11: Wih1 z    f12-13: Whh1 z
//  f14-15: Wih1 n    f16-17: Whh1 n
// packed[((w*18 + f)*512) + lane*8 + j], k = (f&1)*32 + (lane>>4)*8 + j,
// out-row = hb + (lane&15) (+gate offset).
// ---------------------------------------------------------------------------
__global__ void pack_weights_kernel(const float* __restrict__ Whh0,
                                    const float* __restrict__ Wih1,
                                    const float* __restrict__ Whh1,
                                    _Float16* __restrict__ packed)
{
    const int b = blockIdx.x;          // 0..71
    const int w = b / 18, f = b % 18;
    const int l = threadIdx.x;         // 0..63
    const int c = l & 15, g = l >> 4;
    const int hb = w * 16;
    const int kk = f & 1;
    const float* src = Whh0;
    int row = 0;
    switch (f >> 1) {
        case 0: src = Whh0; row = hb + c;        break;
        case 1: src = Whh0; row = 64 + hb + c;   break;
        case 2: src = Whh0; row = 128 + hb + c;  break;
        case 3: src = Wih1; row = hb + c;        break;
        case 4: src = Whh1; row = hb + c;        break;
        case 5: src = Wih1; row = 64 + hb + c;   break;
        case 6: src = Whh1; row = 64 + hb + c;   break;
        case 7: src = Wih1; row = 128 + hb + c;  break;
        case 8: src = Whh1; row = 128 + hb + c;  break;
    }
    _Float16* dst = packed + ((size_t)(w * 18 + f) * 512) + (size_t)l * 8;
    #pragma unroll
    for (int j = 0; j < 8; ++j) {
        int k = kk * 32 + g * 8 + j;
        dst[j] = (_Float16)src[row * 64 + k];
    }
}

// ---------------------------------------------------------------------------
// Layer-pipelined MFMA GRU scan. Block = 16 sequences, 4 waves; wave w owns
// hid-slice w*16..+15. Phase p computes L0(p) AND L1(p-1) concurrently.
// One barrier per phase. Elementwise math uses raw exp2/rcp with biases
// folded into the exp2 argument (VALU-minimal form).
// ---------------------------------------------------------------------------
__global__ __launch_bounds__(256)
void gru_mfma_kernel(const float* __restrict__ x,
                     const _Float16* __restrict__ packedW,
                     const float* __restrict__ Wih0,
                     const float* __restrict__ bih0,
                     const float* __restrict__ bhh0,
                     const float* __restrict__ bih1,
                     const float* __restrict__ bhh1,
                     float* __restrict__ hT_out)
{
    __shared__ __align__(16) _Float16 h0s[2][16][72];   // row stride 144 B
    __shared__ __align__(16) _Float16 h1s[2][16][72];
    __shared__ float xs_[32][17];

    const int tid = threadIdx.x;
    const int l = tid & 63;
    const int w = tid >> 6;
    const int c = l & 15, g = l >> 4;
    const int hb = w * 16;
    const int hid = hb + c;
    const int n0 = blockIdx.x * 16;

    // resident B fragments
    f16x8 B[18];
    {
        const f16x8* bp = (const f16x8*)(packedW + (size_t)w * 18 * 512);
        #pragma unroll
        for (int f = 0; f < 18; ++f) B[f] = bp[f * 64 + l];
    }

    // per-lane constants; sigmoid biases pre-folded by -log2e
    const float wr0 = Wih0[hid], wz0 = Wih0[64 + hid], wn0 = Wih0[128 + hid];
    const float cb0r = NLOG2E * (bhh0[hid] + bih0[hid]);
    const float cb0z = NLOG2E * (bhh0[64 + hid] + bih0[64 + hid]);
    const float b0nh = bhh0[128 + hid];
    const float b0nx = bih0[128 + hid];
    const float cb1r = NLOG2E * (bih1[hid] + bhh1[hid]);
    const float cb1z = NLOG2E * (bih1[64 + hid] + bhh1[64 + hid]);
    const float b1nx = bih1[128 + hid];
    const float b1nh = bhh1[128 + hid];

    for (int p = tid; p < 2 * 16 * 72; p += 256) {
        (&h0s[0][0][0])[p] = (_Float16)0.0f;
        (&h1s[0][0][0])[p] = (_Float16)0.0f;
    }
    float h0st[4] = {0.f, 0.f, 0.f, 0.f};
    float h1st[4] = {0.f, 0.f, 0.f, 0.f};

    auto stage_x = [&](int t0) {
        int ss = tid >> 4;
        int tb = tid & 15;
        xs_[tb][ss]      = x[(size_t)(n0 + ss) * T_ + t0 + tb];
        xs_[tb + 16][ss] = x[(size_t)(n0 + ss) * T_ + t0 + tb + 16];
    };

    const f32x4 zv = {0.f, 0.f, 0.f, 0.f};

    auto phase = [&](int p, bool doL0, bool doL1) {
        const int pp = p & 1;
        const _Float16* h0rd = &h0s[pp ^ 1][0][0];
        // shared A-fragments: h0(p-1) feeds L0 (h-input) and L1 (x-input)
        f16x8 a00 = *(const f16x8*)(h0rd + c * 72 + g * 8);
        f16x8 a01 = *(const f16x8*)(h0rd + c * 72 + 32 + g * 8);

        if (doL0) {
            f32x4 accr = MFMA16(a01, B[1], MFMA16(a00, B[0], zv));
            f32x4 accz = MFMA16(a01, B[3], MFMA16(a00, B[2], zv));
            f32x4 accn = MFMA16(a01, B[5], MFMA16(a00, B[4], zv));

            if (doL1) {
                const _Float16* h1rd = &h1s[pp ^ 1][0][0];
                f16x8 ah0 = *(const f16x8*)(h1rd + c * 72 + g * 8);
                f16x8 ah1 = *(const f16x8*)(h1rd + c * 72 + 32 + g * 8);
                f32x4 r1  = MFMA16(ah1, B[9],  MFMA16(ah0, B[8],
                            MFMA16(a01, B[7],  MFMA16(a00, B[6],  zv))));
                f32x4 z1  = MFMA16(ah1, B[13], MFMA16(ah0, B[12],
                            MFMA16(a01, B[11], MFMA16(a00, B[10], zv))));
                f32x4 xn1 = MFMA16(a01, B[15], MFMA16(a00, B[14], zv));
                f32x4 hn1 = MFMA16(ah1, B[17], MFMA16(ah0, B[16], zv));

                // L0 elementwise -> h0(p)
                #pragma unroll
                for (int q = 0; q < 4; ++q) {
                    int seq = g * 4 + q;
                    float xv = xs_[p & 31][seq];
                    float r = sig_fold(__fmaf_rn(xv, wr0, accr[q]), cb0r);
                    float z = sig_fold(__fmaf_rn(xv, wz0, accz[q]), cb0z);
                    float np = __fmaf_rn(r, accn[q] + b0nh,
                                         __fmaf_rn(xv, wn0, b0nx));
                    float nn = tanh_fast(np);
                    float hn = __fmaf_rn(z, h0st[q] - nn, nn);
                    h0st[q] = hn;
                    h0s[pp][seq][hid] = (_Float16)hn;
                }
                // L1 elementwise -> h1(p-1)
                #pragma unroll
                for (int q = 0; q < 4; ++q) {
                    int seq = g * 4 + q;
                    float r = sig_fold(r1[q], cb1r);
                    float z = sig_fold(z1[q], cb1z);
                    float np = __fmaf_rn(r, hn1[q] + b1nh, xn1[q] + b1nx);
                    float nn = tanh_fast(np);
                    float hn = __fmaf_rn(z, h1st[q] - nn, nn);
                    h1st[q] = hn;
                    h1s[pp][seq][hid] = (_Float16)hn;
                }
            } else {
                #pragma unroll
                for (int q = 0; q < 4; ++q) {
                    int seq = g * 4 + q;
                    float xv = xs_[p & 31][seq];
                    float r = sig_fold(__fmaf_rn(xv, wr0, accr[q]), cb0r);
                    float z = sig_fold(__fmaf_rn(xv, wz0, accz[q]), cb0z);
                    float np = __fmaf_rn(r, accn[q] + b0nh,
                                         __fmaf_rn(xv, wn0, b0nx));
                    float nn = tanh_fast(np);
                    float hn = __fmaf_rn(z, h0st[q] - nn, nn);
                    h0st[q] = hn;
                    h0s[pp][seq][hid] = (_Float16)hn;
                }
            }
        } else {
            // L1 only (final phase p == T_)
            const _Float16* h1rd = &h1s[pp ^ 1][0][0];
            f16x8 ah0 = *(const f16x8*)(h1rd + c * 72 + g * 8);
            f16x8 ah1 = *(const f16x8*)(h1rd + c * 72 + 32 + g * 8);
            f32x4 r1  = MFMA16(ah1, B[9],  MFMA16(ah0, B[8],
                        MFMA16(a01, B[7],  MFMA16(a00, B[6],  zv))));
            f32x4 z1  = MFMA16(ah1, B[13], MFMA16(ah0, B[12],
                        MFMA16(a01, B[11], MFMA16(a00, B[10], zv))));
            f32x4 xn1 = MFMA16(a01, B[15], MFMA16(a00, B[14], zv));
            f32x4 hn1 = MFMA16(ah1, B[17], MFMA16(ah0, B[16], zv));
            #pragma unroll
            for (int q = 0; q < 4; ++q) {
                float r = sig_fold(r1[q], cb1r);
                float z = sig_fold(z1[q], cb1z);
                float np = __fmaf_rn(r, hn1[q] + b1nh, xn1[q] + b1nx);
                float nn = tanh_fast(np);
                float hn = __fmaf_rn(z, h1st[q] - nn, nn);
                h1st[q] = hn;
            }
        }
    };

    // prologue: phase 0 (L0 only)
    stage_x(0);
    __syncthreads();
    phase(0, true, false);

    for (int p = 1; p < T_; ++p) {
        if ((p & 31) == 0) {
            __syncthreads();        // old xs tile fully consumed
            stage_x(p);
        }
        __syncthreads();
        phase(p, true, true);
    }

    // epilogue: phase T (L1 only)
    __syncthreads();
    phase(T_, false, true);

    #pragma unroll
    for (int q = 0; q < 4; ++q) {
        int seq = g * 4 + q;
        hT_out[(size_t)(n0 + seq) * H_ + hid] = h1st[q];
    }
}

// ---------------------------------------------------------------------------
// Heads: mu, softplus(d), v (R=32), resid = y - mu. One thread per sequence.
// ---------------------------------------------------------------------------
__global__ __launch_bounds__(256)
void heads_kernel(const float* __restrict__ hT,
                  const float* __restrict__ y,
                  const float* __restrict__ Wm, const float* __restrict__ bm,
                  const float* __restrict__ Wd, const float* __restrict__ bd,
                  const float* __restrict__ Wv, const float* __restrict__ bv,
                  float* __restrict__ v_out,
                  float* __restrict__ dd_out,
                  float* __restrict__ r_out)
{
    const int n = blockIdx.x * 256 + threadIdx.x;
    const float* h = hT + (size_t)n * H_;

    float hreg[H_];
    #pragma unroll
    for (int j = 0; j < H_; j += 4) {
        float4 q = *(const float4*)(h + j);
        hreg[j] = q.x; hreg[j + 1] = q.y; hreg[j + 2] = q.z; hreg[j + 3] = q.w;
    }
    float mu = bm[0], dv = bd[0];
    #pragma unroll
    for (int j = 0; j < H_; ++j) {
        mu = __fmaf_rn(Wm[j], hreg[j], mu);
        dv = __fmaf_rn(Wd[j], hreg[j], dv);
    }
    r_out[n]  = y[n] - mu;
    dd_out[n] = log1pf(__expf(dv));   // softplus

    for (int k = 0; k < R_; ++k) {
        float acc = bv[k];
        #pragma unroll
        for (int j = 0; j < H_; ++j)
            acc = __fmaf_rn(Wv[k * H_ + j], hreg[j], acc);
        v_out[(size_t)n * R_ + k] = acc;
    }
}

__device__ __forceinline__ float block_reduce_sum256(float* red, int tid, float val)
{
    red[tid] = val;
    __syncthreads();
    for (int off = 128; off > 0; off >>= 1) {
        if (tid < off) red[tid] += red[tid + off];
        __syncthreads();
    }
    float r = red[0];
    __syncthreads();
    return r;
}

// ---------------------------------------------------------------------------
// Per-batch Woodbury: sigma = V V^T + D.
// quad  = r^T D^-1 r - u^T M^-1 u,  u = V^T D^-1 r,  M = I + V^T D^-1 V
// logdet= sum log d + logdet M  (32x32 Cholesky)
// ---------------------------------------------------------------------------
__global__ __launch_bounds__(256)
void woodbury_kernel(const float* __restrict__ v_in,
                     const float* __restrict__ dd_in,
                     const float* __restrict__ r_in,
                     float* __restrict__ batch_out)
{
    __shared__ float Vl[C_][R_ + 1];
    __shared__ float Vw[C_][R_ + 1];
    __shared__ float wi[C_];
    __shared__ float rl[C_];
    __shared__ float red[256];
    __shared__ float MA[R_][R_ + 1];
    __shared__ float uA[R_], yA[R_], wA[R_];

    const int tid = threadIdx.x;
    const int nb  = blockIdx.x * C_;

    for (int p = tid; p < C_ * R_; p += 256) {
        int cc = p >> 5, k = p & 31;
        Vl[cc][k] = v_in[(size_t)(nb + cc) * R_ + k];
    }
    float dval = dd_in[nb + tid];
    float winv = 1.0f / dval;
    float rv   = r_in[nb + tid];
    wi[tid] = winv;
    rl[tid] = rv;
    __syncthreads();

    for (int p = tid; p < C_ * R_; p += 256) {
        int cc = p >> 5, k = p & 31;
        Vw[cc][k] = Vl[cc][k] * wi[cc];
    }
    __syncthreads();

    float slogd = block_reduce_sum256(red, tid, __logf(dval));
    float rDr   = block_reduce_sum256(red, tid, rv * rv * winv);

    #pragma unroll
    for (int e = 0; e < 4; ++e) {
        int p = tid + e * 256;
        int i = p >> 5, j = p & 31;
        float acc = (i == j) ? 1.0f : 0.0f;
        for (int cc = 0; cc < C_; ++cc)
            acc = __fmaf_rn(Vw[cc][i], Vl[cc][j], acc);
        MA[i][j] = acc;
    }
    if (tid < R_) {
        float acc = 0.0f;
        for (int cc = 0; cc < C_; ++cc)
            acc = __fmaf_rn(Vw[cc][tid], rl[cc], acc);
        uA[tid] = acc;
    }
    __syncthreads();

    for (int k = 0; k < R_; ++k) {
        if (tid == 0) MA[k][k] = sqrtf(MA[k][k]);
        __syncthreads();
        if (tid > k && tid < R_) MA[tid][k] /= MA[k][k];
        __syncthreads();
        if (tid > k && tid < R_) {
            float ljk = MA[tid][k];
            for (int i2 = k + 1; i2 <= tid; ++i2)
                MA[tid][i2] -= ljk * MA[i2][k];
        }
        __syncthreads();
    }
    float ldm = block_reduce_sum256(red, tid,
                    (tid < R_) ? 2.0f * __logf(MA[tid][tid]) : 0.0f);

    if (tid == 0) {
        for (int k = 0; k < R_; ++k) {
            float sv = uA[k];
            for (int i2 = 0; i2 < k; ++i2) sv -= MA[k][i2] * yA[i2];
            yA[k] = sv / MA[k][k];
        }
        for (int k = R_ - 1; k >= 0; --k) {
            float sv = yA[k];
            for (int i2 = k + 1; i2 < R_; ++i2) sv -= MA[i2][k] * wA[i2];
            wA[k] = sv / MA[k][k];
        }
        float uw = 0.0f;
        for (int k = 0; k < R_; ++k) uw += wA[k] * uA[k];
        batch_out[blockIdx.x] = (rDr - uw) + slogd + ldm;
    }
}

__global__ void finalize_kernel(const float* __restrict__ bws, float* __restrict__ out)
{
    float v = bws[threadIdx.x];
    #pragma unroll
    for (int off = 32; off > 0; off >>= 1)
        v += __shfl_down(v, off, 64);
    if (threadIdx.x == 0) out[0] = v * (1.0f / 64.0f);
}

} // anonymous namespace

extern "C" void kernel_launch(void* const* d_in, const int* in_sizes, int n_in,
                              void* d_out, int out_size, void* d_ws, size_t ws_size,
                              hipStream_t stream)
{
    const float* x    = (const float*)d_in[0];
    const float* y    = (const float*)d_in[1];
    const float* Wih0 = (const float*)d_in[2];
    const float* Whh0 = (const float*)d_in[3];
    const float* bih0 = (const float*)d_in[4];
    const float* bhh0 = (const float*)d_in[5];
    const float* Wih1 = (const float*)d_in[6];
    const float* Whh1 = (const float*)d_in[7];
    const float* bih1 = (const float*)d_in[8];
    const float* bhh1 = (const float*)d_in[9];
    const float* Wm   = (const float*)d_in[10];
    const float* bm   = (const float*)d_in[11];
    const float* Wd   = (const float*)d_in[12];
    const float* bd   = (const float*)d_in[13];
    const float* Wv   = (const float*)d_in[14];
    const float* bv   = (const float*)d_in[15];

    char* ws = (char*)d_ws;
    float*    hT     = (float*)(ws + 0);                 // N*64 f32   (4 MB)
    float*    v_ws   = (float*)(ws + 4194304);           // N*32 f32   (2 MB)
    float*    dd_ws  = (float*)(ws + 6291456);           // N f32
    float*    r_ws   = (float*)(ws + 6356992);           // N f32
    float*    b_ws   = (float*)(ws + 6422528);           // B f32
    _Float16* packed = (_Float16*)(ws + 6423552);        // 4*18*512 fp16 (73728 B)

    pack_weights_kernel<<<72, 64, 0, stream>>>(Whh0, Wih1, Whh1, packed);
    gru_mfma_kernel<<<N_ / 16, 256, 0, stream>>>(
        x, packed, Wih0, bih0, bhh0, bih1, bhh1, hT);
    heads_kernel<<<N_ / 256, 256, 0, stream>>>(
        hT, y, Wm, bm, Wd, bd, Wv, bv, v_ws, dd_ws, r_ws);
    woodbury_kernel<<<B_, 256, 0, stream>>>(v_ws, dd_ws, r_ws, b_ws);
    finalize_kernel<<<1, 64, 0, stream>>>(b_ws, (float*)d_out);
}

// Round 5
// 1020.592 us; speedup vs baseline: 1.8141x; 1.0890x over previous
//
#include <hip/hip_runtime.h>

typedef __attribute__((ext_vector_type(8))) _Float16 f16x8;
typedef __attribute__((ext_vector_type(4))) float f32x4;

namespace {

constexpr int H_ = 64;
constexpr int R_ = 32;
constexpr int B_ = 64;
constexpr int C_ = 256;
constexpr int T_ = 512;
constexpr int N_ = B_ * C_;   // 16384 sequences

constexpr float NLOG2E  = -1.44269504088896f;
constexpr float N2LOG2E = -2.88539008177793f;

#define MFMA16(a, b, c) __builtin_amdgcn_mfma_f32_16x16x32_f16((a), (b), (c), 0, 0, 0)

// sigmoid(pre + bias) with bias pre-folded: cb = -log2e * bias
__device__ __forceinline__ float sig_fold(float pre, float cb) {
    float t = __builtin_amdgcn_exp2f(__fmaf_rn(pre, NLOG2E, cb));
    return __builtin_amdgcn_rcpf(1.0f + t);
}
// tanh(a) = 2*sigmoid(2a) - 1
__device__ __forceinline__ float tanh_fast(float a) {
    float t = __builtin_amdgcn_exp2f(a * N2LOG2E);
    return __fmaf_rn(2.0f, __builtin_amdgcn_rcpf(1.0f + t), -1.0f);
}

// ---------------------------------------------------------------------------
// Pack GRU weights into B-fragment-linear fp16.
//  f0-1 : Whh0 r     f2-3 : Whh0 z     f4-5 : Whh0 n
//  f6-7 : Wih1 r     f8-9 : Whh1 r
//  f10-11: Wih1 z    f12-13: Whh1 z
//  f14-15: Wih1 n    f16-17: Whh1 n
// packed[((w*18 + f)*512) + lane*8 + j], k = (f&1)*32 + (lane>>4)*8 + j,
// out-row = hb + (lane&15) (+gate offset).
// ---------------------------------------------------------------------------
__global__ void pack_weights_kernel(const float* __restrict__ Whh0,
                                    const float* __restrict__ Wih1,
                                    const float* __restrict__ Whh1,
                                    _Float16* __restrict__ packed)
{
    const int b = blockIdx.x;          // 0..71
    const int w = b / 18, f = b % 18;
    const int l = threadIdx.x;         // 0..63
    const int c = l & 15, g = l >> 4;
    const int hb = w * 16;
    const int kk = f & 1;
    const float* src = Whh0;
    int row = 0;
    switch (f >> 1) {
        case 0: src = Whh0; row = hb + c;        break;
        case 1: src = Whh0; row = 64 + hb + c;   break;
        case 2: src = Whh0; row = 128 + hb + c;  break;
        case 3: src = Wih1; row = hb + c;        break;
        case 4: src = Whh1; row = hb + c;        break;
        case 5: src = Wih1; row = 64 + hb + c;   break;
        case 6: src = Whh1; row = 64 + hb + c;   break;
        case 7: src = Wih1; row = 128 + hb + c;  break;
        case 8: src = Whh1; row = 128 + hb + c;  break;
    }
    _Float16* dst = packed + ((size_t)(w * 18 + f) * 512) + (size_t)l * 8;
    #pragma unroll
    for (int j = 0; j < 8; ++j) {
        int k = kk * 32 + g * 8 + j;
        dst[j] = (_Float16)src[row * 64 + k];
    }
}

// ---------------------------------------------------------------------------
// Layer-pipelined MFMA GRU scan. Block = 16 sequences, 4 waves; wave w owns
// hid-slice w*16..+15. Phase p computes L0(p) AND L1(p-1) concurrently.
// __launch_bounds__(256,3): 168-VGPR budget so the 18 B-fragments stay
// truly register-resident (at (256,default) the allocator reloads them
// every phase). Loop 2x-unrolled so buffer parity (and thus every LDS base
// address) is compile-time constant.
// ---------------------------------------------------------------------------

// PHASE(PP, DT, DOL0, DOL1): one pipeline phase with compile-time parity PP.
// MFMA order: L0 -> L1 r/z -> L0 elementwise -> L1 xn/hn -> L1 elementwise
// (keeps peak register pressure low; elementwise hides MFMA latency).
#define PHASE(PP, DT, DOL0, DOL1)                                             \
  do {                                                                        \
    const _Float16* h0rd = &h0s[(PP) ^ 1][0][0];                              \
    f16x8 a00 = *(const f16x8*)(h0rd + c * 72 + g * 8);                       \
    f16x8 a01 = *(const f16x8*)(h0rd + c * 72 + 32 + g * 8);                  \
    if (DOL0) {                                                               \
      f32x4 accr = MFMA16(a01, B[1], MFMA16(a00, B[0], zv));                  \
      f32x4 accz = MFMA16(a01, B[3], MFMA16(a00, B[2], zv));                  \
      f32x4 accn = MFMA16(a01, B[5], MFMA16(a00, B[4], zv));                  \
      if (DOL1) {                                                             \
        const _Float16* h1rd = &h1s[(PP) ^ 1][0][0];                          \
        f16x8 ah0 = *(const f16x8*)(h1rd + c * 72 + g * 8);                   \
        f16x8 ah1 = *(const f16x8*)(h1rd + c * 72 + 32 + g * 8);              \
        f32x4 r1  = MFMA16(ah1, B[9],  MFMA16(ah0, B[8],                      \
                    MFMA16(a01, B[7],  MFMA16(a00, B[6],  zv))));             \
        f32x4 z1  = MFMA16(ah1, B[13], MFMA16(ah0, B[12],                     \
                    MFMA16(a01, B[11], MFMA16(a00, B[10], zv))));             \
        _Pragma("unroll")                                                     \
        for (int q = 0; q < 4; ++q) {                                         \
          int seq = g * 4 + q;                                                \
          float xv = xs_[DT][seq];                                            \
          float r = sig_fold(__fmaf_rn(xv, wr0, accr[q]), cb0r);              \
          float z = sig_fold(__fmaf_rn(xv, wz0, accz[q]), cb0z);              \
          float np = __fmaf_rn(r, accn[q] + b0nh, __fmaf_rn(xv, wn0, b0nx));  \
          float nn = tanh_fast(np);                                           \
          float hn = __fmaf_rn(z, h0st[q] - nn, nn);                          \
          h0st[q] = hn;                                                       \
          h0s[PP][seq][hid] = (_Float16)hn;                                   \
        }                                                                     \
        f32x4 xn1 = MFMA16(a01, B[15], MFMA16(a00, B[14], zv));               \
        f32x4 hn1 = MFMA16(ah1, B[17], MFMA16(ah0, B[16], zv));               \
        _Pragma("unroll")                                                     \
        for (int q = 0; q < 4; ++q) {                                         \
          int seq = g * 4 + q;                                                \
          float r = sig_fold(r1[q], cb1r);                                    \
          float z = sig_fold(z1[q], cb1z);                                    \
          float np = __fmaf_rn(r, hn1[q] + b1nh, xn1[q] + b1nx);              \
          float nn = tanh_fast(np);                                           \
          float hn = __fmaf_rn(z, h1st[q] - nn, nn);                          \
          h1st[q] = hn;                                                       \
          h1s[PP][seq][hid] = (_Float16)hn;                                   \
        }                                                                     \
      } else {                                                                \
        _Pragma("unroll")                                                     \
        for (int q = 0; q < 4; ++q) {                                         \
          int seq = g * 4 + q;                                                \
          float xv = xs_[DT][seq];                                            \
          float r = sig_fold(__fmaf_rn(xv, wr0, accr[q]), cb0r);              \
          float z = sig_fold(__fmaf_rn(xv, wz0, accz[q]), cb0z);              \
          float np = __fmaf_rn(r, accn[q] + b0nh, __fmaf_rn(xv, wn0, b0nx));  \
          float nn = tanh_fast(np);                                           \
          float hn = __fmaf_rn(z, h0st[q] - nn, nn);                          \
          h0st[q] = hn;                                                       \
          h0s[PP][seq][hid] = (_Float16)hn;                                   \
        }                                                                     \
      }                                                                       \
    } else {                                                                  \
      const _Float16* h1rd = &h1s[(PP) ^ 1][0][0];                            \
      f16x8 ah0 = *(const f16x8*)(h1rd + c * 72 + g * 8);                     \
      f16x8 ah1 = *(const f16x8*)(h1rd + c * 72 + 32 + g * 8);                \
      f32x4 r1  = MFMA16(ah1, B[9],  MFMA16(ah0, B[8],                        \
                  MFMA16(a01, B[7],  MFMA16(a00, B[6],  zv))));               \
      f32x4 z1  = MFMA16(ah1, B[13], MFMA16(ah0, B[12],                       \
                  MFMA16(a01, B[11], MFMA16(a00, B[10], zv))));               \
      f32x4 xn1 = MFMA16(a01, B[15], MFMA16(a00, B[14], zv));                 \
      f32x4 hn1 = MFMA16(ah1, B[17], MFMA16(ah0, B[16], zv));                 \
      _Pragma("unroll")                                                       \
      for (int q = 0; q < 4; ++q) {                                           \
        float r = sig_fold(r1[q], cb1r);                                      \
        float z = sig_fold(z1[q], cb1z);                                      \
        float np = __fmaf_rn(r, hn1[q] + b1nh, xn1[q] + b1nx);                \
        float nn = tanh_fast(np);                                             \
        float hn = __fmaf_rn(z, h1st[q] - nn, nn);                            \
        h1st[q] = hn;                                                         \
      }                                                                       \
    }                                                                         \
  } while (0)

__global__ __launch_bounds__(256, 3)
void gru_mfma_kernel(const float* __restrict__ x,
                     const _Float16* __restrict__ packedW,
                     const float* __restrict__ Wih0,
                     const float* __restrict__ bih0,
                     const float* __restrict__ bhh0,
                     const float* __restrict__ bih1,
                     const float* __restrict__ bhh1,
                     float* __restrict__ hT_out)
{
    __shared__ __align__(16) _Float16 h0s[2][16][72];   // row stride 144 B
    __shared__ __align__(16) _Float16 h1s[2][16][72];
    __shared__ float xs_[32][17];

    const int tid = threadIdx.x;
    const int l = tid & 63;
    const int w = tid >> 6;
    const int c = l & 15, g = l >> 4;
    const int hb = w * 16;
    const int hid = hb + c;
    const int n0 = blockIdx.x * 16;

    // resident B fragments (72 VGPR — the point of launch_bounds(256,3))
    f16x8 B[18];
    {
        const f16x8* bp = (const f16x8*)(packedW + (size_t)w * 18 * 512);
        #pragma unroll
        for (int f = 0; f < 18; ++f) B[f] = bp[f * 64 + l];
    }

    // per-lane constants; sigmoid biases pre-folded by -log2e
    const float wr0 = Wih0[hid], wz0 = Wih0[64 + hid], wn0 = Wih0[128 + hid];
    const float cb0r = NLOG2E * (bhh0[hid] + bih0[hid]);
    const float cb0z = NLOG2E * (bhh0[64 + hid] + bih0[64 + hid]);
    const float b0nh = bhh0[128 + hid];
    const float b0nx = bih0[128 + hid];
    const float cb1r = NLOG2E * (bih1[hid] + bhh1[hid]);
    const float cb1z = NLOG2E * (bih1[64 + hid] + bhh1[64 + hid]);
    const float b1nx = bih1[128 + hid];
    const float b1nh = bhh1[128 + hid];

    for (int p = tid; p < 2 * 16 * 72; p += 256) {
        (&h0s[0][0][0])[p] = (_Float16)0.0f;
        (&h1s[0][0][0])[p] = (_Float16)0.0f;
    }
    float h0st[4] = {0.f, 0.f, 0.f, 0.f};
    float h1st[4] = {0.f, 0.f, 0.f, 0.f};

    auto stage_x = [&](int t0) {
        int ss = tid >> 4;
        int tb = tid & 15;
        xs_[tb][ss]      = x[(size_t)(n0 + ss) * T_ + t0 + tb];
        xs_[tb + 16][ss] = x[(size_t)(n0 + ss) * T_ + t0 + tb + 16];
    };

    const f32x4 zv = {0.f, 0.f, 0.f, 0.f};

    // prologue: phase 0 (L0 only), parity 0
    stage_x(0);
    __syncthreads();
    PHASE(0, 0, true, false);

    // main loop: phases 1..510 in parity-static pairs (odd, even)
    for (int p = 1; p < T_ - 1; p += 2) {
        __syncthreads();
        PHASE(1, p & 31, true, true);
        if (((p + 1) & 31) == 0) {
            __syncthreads();        // old xs tile fully consumed
            stage_x(p + 1);
        }
        __syncthreads();
        PHASE(0, (p + 1) & 31, true, true);
    }

    // leftover phase 511 (parity 1)
    __syncthreads();
    PHASE(1, 31, true, true);

    // epilogue: phase 512 (L1 only), parity 0
    __syncthreads();
    PHASE(0, 0, false, true);

    #pragma unroll
    for (int q = 0; q < 4; ++q) {
        int seq = g * 4 + q;
        hT_out[(size_t)(n0 + seq) * H_ + hid] = h1st[q];
    }
}

// ---------------------------------------------------------------------------
// Heads: mu, softplus(d), v (R=32), resid = y - mu. One thread per sequence.
// ---------------------------------------------------------------------------
__global__ __launch_bounds__(256)
void heads_kernel(const float* __restrict__ hT,
                  const float* __restrict__ y,
                  const float* __restrict__ Wm, const float* __restrict__ bm,
                  const float* __restrict__ Wd, const float* __restrict__ bd,
                  const float* __restrict__ Wv, const float* __restrict__ bv,
                  float* __restrict__ v_out,
                  float* __restrict__ dd_out,
                  float* __restrict__ r_out)
{
    const int n = blockIdx.x * 256 + threadIdx.x;
    const float* h = hT + (size_t)n * H_;

    float hreg[H_];
    #pragma unroll
    for (int j = 0; j < H_; j += 4) {
        float4 q = *(const float4*)(h + j);
        hreg[j] = q.x; hreg[j + 1] = q.y; hreg[j + 2] = q.z; hreg[j + 3] = q.w;
    }
    float mu = bm[0], dv = bd[0];
    #pragma unroll
    for (int j = 0; j < H_; ++j) {
        mu = __fmaf_rn(Wm[j], hreg[j], mu);
        dv = __fmaf_rn(Wd[j], hreg[j], dv);
    }
    r_out[n]  = y[n] - mu;
    dd_out[n] = log1pf(__expf(dv));   // softplus

    for (int k = 0; k < R_; ++k) {
        float acc = bv[k];
        #pragma unroll
        for (int j = 0; j < H_; ++j)
            acc = __fmaf_rn(Wv[k * H_ + j], hreg[j], acc);
        v_out[(size_t)n * R_ + k] = acc;
    }
}

__device__ __forceinline__ float block_reduce_sum256(float* red, int tid, float val)
{
    red[tid] = val;
    __syncthreads();
    for (int off = 128; off > 0; off >>= 1) {
        if (tid < off) red[tid] += red[tid + off];
        __syncthreads();
    }
    float r = red[0];
    __syncthreads();
    return r;
}

// ---------------------------------------------------------------------------
// Per-batch Woodbury: sigma = V V^T + D.
// quad  = r^T D^-1 r - u^T M^-1 u,  u = V^T D^-1 r,  M = I + V^T D^-1 V
// logdet= sum log d + logdet M  (32x32 Cholesky)
// ---------------------------------------------------------------------------
__global__ __launch_bounds__(256)
void woodbury_kernel(const float* __restrict__ v_in,
                     const float* __restrict__ dd_in,
                     const float* __restrict__ r_in,
                     float* __restrict__ batch_out)
{
    __shared__ float Vl[C_][R_ + 1];
    __shared__ float Vw[C_][R_ + 1];
    __shared__ float wi[C_];
    __shared__ float rl[C_];
    __shared__ float red[256];
    __shared__ float MA[R_][R_ + 1];
    __shared__ float uA[R_], yA[R_], wA[R_];

    const int tid = threadIdx.x;
    const int nb  = blockIdx.x * C_;

    for (int p = tid; p < C_ * R_; p += 256) {
        int cc = p >> 5, k = p & 31;
        Vl[cc][k] = v_in[(size_t)(nb + cc) * R_ + k];
    }
    float dval = dd_in[nb + tid];
    float winv = 1.0f / dval;
    float rv   = r_in[nb + tid];
    wi[tid] = winv;
    rl[tid] = rv;
    __syncthreads();

    for (int p = tid; p < C_ * R_; p += 256) {
        int cc = p >> 5, k = p & 31;
        Vw[cc][k] = Vl[cc][k] * wi[cc];
    }
    __syncthreads();

    float slogd = block_reduce_sum256(red, tid, __logf(dval));
    float rDr   = block_reduce_sum256(red, tid, rv * rv * winv);

    #pragma unroll
    for (int e = 0; e < 4; ++e) {
        int p = tid + e * 256;
        int i = p >> 5, j = p & 31;
        float acc = (i == j) ? 1.0f : 0.0f;
        for (int cc = 0; cc < C_; ++cc)
            acc = __fmaf_rn(Vw[cc][i], Vl[cc][j], acc);
        MA[i][j] = acc;
    }
    if (tid < R_) {
        float acc = 0.0f;
        for (int cc = 0; cc < C_; ++cc)
            acc = __fmaf_rn(Vw[cc][tid], rl[cc], acc);
        uA[tid] = acc;
    }
    __syncthreads();

    for (int k = 0; k < R_; ++k) {
        if (tid == 0) MA[k][k] = sqrtf(MA[k][k]);
        __syncthreads();
        if (tid > k && tid < R_) MA[tid][k] /= MA[k][k];
        __syncthreads();
        if (tid > k && tid < R_) {
            float ljk = MA[tid][k];
            for (int i2 = k + 1; i2 <= tid; ++i2)
                MA[tid][i2] -= ljk * MA[i2][k];
        }
        __syncthreads();
    }
    float ldm = block_reduce_sum256(red, tid,
                    (tid < R_) ? 2.0f * __logf(MA[tid][tid]) : 0.0f);

    if (tid == 0) {
        for (int k = 0; k < R_; ++k) {
            float sv = uA[k];
            for (int i2 = 0; i2 < k; ++i2) sv -= MA[k][i2] * yA[i2];
            yA[k] = sv / MA[k][k];
        }
        for (int k = R_ - 1; k >= 0; --k) {
            float sv = yA[k];
            for (int i2 = k + 1; i2 < R_; ++i2) sv -= MA[i2][k] * wA[i2];
            wA[k] = sv / MA[k][k];
        }
        float uw = 0.0f;
        for (int k = 0; k < R_; ++k) uw += wA[k] * uA[k];
        batch_out[blockIdx.x] = (rDr - uw) + slogd + ldm;
    }
}

__global__ void finalize_kernel(const float* __restrict__ bws, float* __restrict__ out)
{
    float v = bws[threadIdx.x];
    #pragma unroll
    for (int off = 32; off > 0; off >>= 1)
        v += __shfl_down(v, off, 64);
    if (threadIdx.x == 0) out[0] = v * (1.0f / 64.0f);
}

} // anonymous namespace

extern "C" void kernel_launch(void* const* d_in, const int* in_sizes, int n_in,
                              void* d_out, int out_size, void* d_ws, size_t ws_size,
                              hipStream_t stream)
{
    const float* x    = (const float*)d_in[0];
    const float* y    = (const float*)d_in[1];
    const float* Wih0 = (const float*)d_in[2];
    const float* Whh0 = (const float*)d_in[3];
    const float* bih0 = (const float*)d_in[4];
    const float* bhh0 = (const float*)d_in[5];
    const float* Wih1 = (const float*)d_in[6];
    const float* Whh1 = (const float*)d_in[7];
    const float* bih1 = (const float*)d_in[8];
    const float* bhh1 = (const float*)d_in[9];
    const float* Wm   = (const float*)d_in[10];
    const float* bm   = (const float*)d_in[11];
    const float* Wd   = (const float*)d_in[12];
    const float* bd   = (const float*)d_in[13];
    const float* Wv   = (const float*)d_in[14];
    const float* bv   = (const float*)d_in[15];

    char* ws = (char*)d_ws;
    float*    hT     = (float*)(ws + 0);                 // N*64 f32   (4 MB)
    float*    v_ws   = (float*)(ws + 4194304);           // N*32 f32   (2 MB)
    float*    dd_ws  = (float*)(ws + 6291456);           // N f32
    float*    r_ws   = (float*)(ws + 6356992);           // N f32
    float*    b_ws   = (float*)(ws + 6422528);           // B f32
    _Float16* packed = (_Float16*)(ws + 6423552);        // 4*18*512 fp16 (73728 B)

    pack_weights_kernel<<<72, 64, 0, stream>>>(Whh0, Wih1, Whh1, packed);
    gru_mfma_kernel<<<N_ / 16, 256, 0, stream>>>(
        x, packed, Wih0, bih0, bhh0, bih1, bhh1, hT);
    heads_kernel<<<N_ / 256, 256, 0, stream>>>(
        hT, y, Wm, bm, Wd, bd, Wv, bv, v_ws, dd_ws, r_ws);
    woodbury_kernel<<<B_, 256, 0, stream>>>(v_ws, dd_ws, r_ws, b_ws);
    finalize_kernel<<<1, 64, 0, stream>>>(b_ws, (float*)d_out);
}